// Round 1
// baseline (161.668 us; speedup 1.0000x reference)
//
#include <hip/hip_runtime.h>

// Problem constants (setup_inputs: B=256, T=16, H=W=160, sms=2 -> t=16, h=w=80)
#define T_DIM 16
#define H2 80
#define W2 80
#define SLICE (H2 * W2)          // 6400 floats per t-slice
#define SAMPLE (T_DIM * SLICE)   // 102400 floats per sample
#define BANDS 5                  // row-bands per sample
#define ROWS_PER_BAND (H2 / BANDS)  // 16 rows
#define BLOCK (ROWS_PER_BAND * W2 / 4)  // 320 threads, one float4 each per slice

// Phase 1: per-sample linear sums (S0, Sx, Sy, Sq) + TV sums (h, w, t),
// accumulated via atomics into ws[b*8 + 0..6].
__global__ __launch_bounds__(BLOCK) void tsr_phase1(const float* __restrict__ scores,
                                                    float* __restrict__ ws) {
    __shared__ float lds[(ROWS_PER_BAND + 1) * W2];  // band slice + halo row (1360 floats)
    __shared__ float red[(BLOCK / 64) * 7];

    const int blk  = blockIdx.x;
    const int b    = blk / BANDS;
    const int band = blk % BANDS;
    const int tid  = threadIdx.x;

    const int y0  = band * ROWS_PER_BAND;
    const int r   = tid / (W2 / 4);   // local row 0..15
    const int cx  = tid % (W2 / 4);   // float4 index within row, 0..19
    const int y   = y0 + r;
    const int xb  = cx * 4;
    const int pos = tid * 4;          // band-local flat position (floats)

    const float step = 2.0f / (float)(H2 - 1);   // h == w == 80 -> same step
    const float yy  = -1.0f + (float)y * step;
    const float xx0 = -1.0f + (float)(xb + 0) * step;
    const float xx1 = -1.0f + (float)(xb + 1) * step;
    const float xx2 = -1.0f + (float)(xb + 2) * step;
    const float xx3 = -1.0f + (float)(xb + 3) * step;
    const float yy2 = yy * yy;
    const float cq0 = xx0 * xx0 + yy2;
    const float cq1 = xx1 * xx1 + yy2;
    const float cq2 = xx2 * xx2 + yy2;
    const float cq3 = xx3 * xx3 + yy2;

    const float4* base = (const float4*)(scores + (size_t)b * SAMPLE);
    const int f4idx = band * BLOCK + tid;  // slice-local float4 index of my element
    const bool halo = (y0 + ROWS_PER_BAND < H2) && (tid < W2 / 4);
    const int haloIdx = (y0 + ROWS_PER_BAND) * (W2 / 4) + tid;

    const bool wavail = (xb + 4 < W2);   // float4-boundary w-diff exists
    const bool havail = (y + 1 < H2);    // h-diff exists

    float s0 = 0.f, sx = 0.f, sy = 0.f, sq = 0.f;
    float tvh = 0.f, tvw = 0.f, tvt = 0.f;
    float4 prev = make_float4(0.f, 0.f, 0.f, 0.f);

    for (int t = 0; t < T_DIM; ++t) {
        const float4* sl = base + (size_t)t * (SLICE / 4);
        float4 v = sl[f4idx];
        v.x = fmaxf(v.x, 0.f); v.y = fmaxf(v.y, 0.f);
        v.z = fmaxf(v.z, 0.f); v.w = fmaxf(v.w, 0.f);
        float4 hv;
        if (halo) {
            hv = sl[haloIdx];
            hv.x = fmaxf(hv.x, 0.f); hv.y = fmaxf(hv.y, 0.f);
            hv.z = fmaxf(hv.z, 0.f); hv.w = fmaxf(hv.w, 0.f);
        }
        __syncthreads();  // previous iteration's LDS reads are done
        *(float4*)&lds[pos] = v;
        if (halo) *(float4*)&lds[ROWS_PER_BAND * W2 + tid * 4] = hv;
        __syncthreads();

        // linear sums
        const float rs = v.x + v.y + v.z + v.w;
        s0 += rs;
        sy = fmaf(yy, rs, sy);
        sx = fmaf(xx0, v.x, sx); sx = fmaf(xx1, v.y, sx);
        sx = fmaf(xx2, v.z, sx); sx = fmaf(xx3, v.w, sx);
        sq = fmaf(cq0, v.x, sq); sq = fmaf(cq1, v.y, sq);
        sq = fmaf(cq2, v.z, sq); sq = fmaf(cq3, v.w, sq);

        // w-diffs: 3 internal + boundary element from LDS
        tvw += fabsf(v.y - v.x) + fabsf(v.z - v.y) + fabsf(v.w - v.z);
        if (wavail) tvw += fabsf(lds[pos + 4] - v.w);

        // h-diffs: row y+1 from LDS (halo row covers local row 15)
        if (havail) {
            const float4 d = *(const float4*)&lds[pos + W2];
            tvh += fabsf(d.x - v.x) + fabsf(d.y - v.y) +
                   fabsf(d.z - v.z) + fabsf(d.w - v.w);
        }

        // t-diffs: fully register-resident
        if (t > 0) {
            tvt += fabsf(v.x - prev.x) + fabsf(v.y - prev.y) +
                   fabsf(v.z - prev.z) + fabsf(v.w - prev.w);
        }
        prev = v;
    }

    // block reduction: wave shuffle, then cross-wave via LDS
    float acc[7] = {s0, sx, sy, sq, tvh, tvw, tvt};
#pragma unroll
    for (int off = 32; off > 0; off >>= 1) {
#pragma unroll
        for (int i = 0; i < 7; ++i) acc[i] += __shfl_down(acc[i], off);
    }
    const int wave = tid >> 6;
    const int lane = tid & 63;
    __syncthreads();  // done with lds slice buffer (red is separate but keep order clean)
    if (lane == 0) {
#pragma unroll
        for (int i = 0; i < 7; ++i) red[wave * 7 + i] = acc[i];
    }
    __syncthreads();
    if (tid < 7) {
        float v = 0.f;
#pragma unroll
        for (int wv = 0; wv < BLOCK / 64; ++wv) v += red[wv * 7 + tid];
        atomicAdd(&ws[b * 8 + tid], v);
    }
}

// Phase 2: per-sample nonlinear combine + batch mean -> scalar
__global__ __launch_bounds__(256) void tsr_finalize(const float* __restrict__ ws,
                                                    float* __restrict__ out, int B) {
    __shared__ float red[256];
    const int tid = threadIdx.x;
    float acc = 0.f;
    const float ch = 1.0f / (float)(T_DIM * (H2 - 1) * W2);       // 1/101120
    const float cw = 1.0f / (float)(T_DIM * H2 * (W2 - 1));       // 1/101120
    const float ct = 0.3f / (float)((T_DIM - 1) * H2 * W2);       // 0.3/96000
    for (int b = tid; b < B; b += 256) {
        const float* w = ws + b * 8;
        const float S0 = w[0], Sx = w[1], Sy = w[2], Sq = w[3];
        const float Th = w[4], Tw = w[5], Tt = w[6];
        const float tot = fmaxf(S0, 1e-6f);
        const float inv = 1.0f / tot;
        const float mux = Sx * inv, muy = Sy * inv;
        const float m2 = mux * mux + muy * muy;
        const float compact = Sq * inv - 2.0f * m2 + m2 * (S0 * inv);
        const float tv = Th * ch + Tw * cw + Tt * ct;
        acc += compact + tv;
    }
    red[tid] = acc;
    __syncthreads();
    for (int s = 128; s > 0; s >>= 1) {
        if (tid < s) red[tid] += red[tid + s];
        __syncthreads();
    }
    if (tid == 0) out[0] = red[0] / (float)B;
}

extern "C" void kernel_launch(void* const* d_in, const int* in_sizes, int n_in,
                              void* d_out, int out_size, void* d_ws, size_t ws_size,
                              hipStream_t stream) {
    const float* scores = (const float*)d_in[0];
    const int B = in_sizes[0] / SAMPLE;  // 256
    float* ws = (float*)d_ws;

    // ws is re-poisoned to 0xAA before every launch -> zero the accumulators
    hipMemsetAsync(ws, 0, (size_t)B * 8 * sizeof(float), stream);

    tsr_phase1<<<B * BANDS, BLOCK, 0, stream>>>(scores, ws);
    tsr_finalize<<<1, 256, 0, stream>>>(ws, (float*)d_out, B);
}

// Round 2
// 159.980 us; speedup vs baseline: 1.0105x; 1.0105x over previous
//
#include <hip/hip_runtime.h>

// Problem constants (setup_inputs: B=256, T=16, H=W=160, sms=2 -> t=16, h=w=80)
#define T_DIM 16
#define H2 80
#define W2 80
#define SLICE (H2 * W2)          // 6400 floats per t-slice
#define SAMPLE (T_DIM * SLICE)   // 102400 floats per sample
#define BANDS 5                  // row-bands per sample
#define ROWS_PER_BAND (H2 / BANDS)  // 16 rows
#define BLOCK (ROWS_PER_BAND * W2 / 4)  // 320 threads, one float4 each per slice

__device__ __forceinline__ float4 relu4(float4 v) {
    v.x = fmaxf(v.x, 0.f); v.y = fmaxf(v.y, 0.f);
    v.z = fmaxf(v.z, 0.f); v.w = fmaxf(v.w, 0.f);
    return v;
}

// Phase 1: per-sample linear sums (S0, Sx, Sy, Sq) + TV sums (h, w, t).
// Each block writes its 7 partials to ws[blockIdx.x*8 + 0..6] (no init needed).
// t-loop is software-pipelined: t+1's global loads are issued BEFORE the
// barriers/compute of t, so they stay in flight across __syncthreads.
__global__ __launch_bounds__(BLOCK) void tsr_phase1(const float* __restrict__ scores,
                                                    float* __restrict__ ws) {
    __shared__ float lds[(ROWS_PER_BAND + 1) * W2];  // band slice + halo row (1360 floats)
    __shared__ float red[(BLOCK / 64) * 7];

    const int blk  = blockIdx.x;
    const int b    = blk / BANDS;
    const int band = blk % BANDS;
    const int tid  = threadIdx.x;

    const int y0  = band * ROWS_PER_BAND;
    const int r   = tid / (W2 / 4);   // local row 0..15
    const int cx  = tid % (W2 / 4);   // float4 index within row, 0..19
    const int y   = y0 + r;
    const int xb  = cx * 4;
    const int pos = tid * 4;          // band-local flat position (floats)

    const float step = 2.0f / (float)(H2 - 1);   // h == w == 80 -> same step
    const float yy  = -1.0f + (float)y * step;
    const float xx0 = -1.0f + (float)(xb + 0) * step;
    const float xx1 = -1.0f + (float)(xb + 1) * step;
    const float xx2 = -1.0f + (float)(xb + 2) * step;
    const float xx3 = -1.0f + (float)(xb + 3) * step;
    const float yy2 = yy * yy;
    const float cq0 = xx0 * xx0 + yy2;
    const float cq1 = xx1 * xx1 + yy2;
    const float cq2 = xx2 * xx2 + yy2;
    const float cq3 = xx3 * xx3 + yy2;

    const float4* base = (const float4*)(scores + (size_t)b * SAMPLE);
    const int f4idx = band * BLOCK + tid;  // slice-local float4 index of my element
    const bool halo = (y0 + ROWS_PER_BAND < H2) && (tid < W2 / 4);
    const int haloIdx = (y0 + ROWS_PER_BAND) * (W2 / 4) + tid;

    const bool wavail = (xb + 4 < W2);   // float4-boundary w-diff exists
    const bool havail = (y + 1 < H2);    // h-diff exists

    float s0 = 0.f, sx = 0.f, sy = 0.f, sq = 0.f;
    float tvh = 0.f, tvw = 0.f, tvt = 0.f;
    float4 prev = make_float4(0.f, 0.f, 0.f, 0.f);

    // Prologue: load t=0
    float4 v = relu4(base[f4idx]);
    float4 hv = make_float4(0.f, 0.f, 0.f, 0.f);
    if (halo) hv = relu4(base[haloIdx]);

    for (int t = 0; t < T_DIM; ++t) {
        // Prefetch t+1 (issued before barriers -> stays in flight across them)
        float4 vn = make_float4(0.f, 0.f, 0.f, 0.f);
        float4 hvn = make_float4(0.f, 0.f, 0.f, 0.f);
        if (t + 1 < T_DIM) {
            const float4* sln = base + (size_t)(t + 1) * (SLICE / 4);
            vn = sln[f4idx];
            if (halo) hvn = sln[haloIdx];
        }

        __syncthreads();  // previous iteration's LDS reads are done
        *(float4*)&lds[pos] = v;
        if (halo) *(float4*)&lds[ROWS_PER_BAND * W2 + tid * 4] = hv;
        __syncthreads();

        // linear sums
        const float rs = v.x + v.y + v.z + v.w;
        s0 += rs;
        sy = fmaf(yy, rs, sy);
        sx = fmaf(xx0, v.x, sx); sx = fmaf(xx1, v.y, sx);
        sx = fmaf(xx2, v.z, sx); sx = fmaf(xx3, v.w, sx);
        sq = fmaf(cq0, v.x, sq); sq = fmaf(cq1, v.y, sq);
        sq = fmaf(cq2, v.z, sq); sq = fmaf(cq3, v.w, sq);

        // w-diffs: 3 internal + boundary element from LDS
        tvw += fabsf(v.y - v.x) + fabsf(v.z - v.y) + fabsf(v.w - v.z);
        if (wavail) tvw += fabsf(lds[pos + 4] - v.w);

        // h-diffs: row y+1 from LDS (halo row covers local row 15)
        if (havail) {
            const float4 d = *(const float4*)&lds[pos + W2];
            tvh += fabsf(d.x - v.x) + fabsf(d.y - v.y) +
                   fabsf(d.z - v.z) + fabsf(d.w - v.w);
        }

        // t-diffs: fully register-resident
        if (t > 0) {
            tvt += fabsf(v.x - prev.x) + fabsf(v.y - prev.y) +
                   fabsf(v.z - prev.z) + fabsf(v.w - prev.w);
        }
        prev = v;

        // Consume prefetch (vmcnt wait lands here, after a full iteration of work)
        v = relu4(vn);
        if (halo) hv = relu4(hvn);
    }

    // block reduction: wave shuffle, then cross-wave via LDS
    float acc[7] = {s0, sx, sy, sq, tvh, tvw, tvt};
#pragma unroll
    for (int off = 32; off > 0; off >>= 1) {
#pragma unroll
        for (int i = 0; i < 7; ++i) acc[i] += __shfl_down(acc[i], off);
    }
    const int wave = tid >> 6;
    const int lane = tid & 63;
    __syncthreads();
    if (lane == 0) {
#pragma unroll
        for (int i = 0; i < 7; ++i) red[wave * 7 + i] = acc[i];
    }
    __syncthreads();
    if (tid < 7) {
        float s = 0.f;
#pragma unroll
        for (int wv = 0; wv < BLOCK / 64; ++wv) s += red[wv * 7 + tid];
        ws[blk * 8 + tid] = s;  // plain store to a distinct slot -> no init, no atomics
    }
}

// Phase 2: sum band partials per sample, nonlinear combine, batch mean -> scalar
__global__ __launch_bounds__(256) void tsr_finalize(const float* __restrict__ ws,
                                                    float* __restrict__ out, int B) {
    __shared__ float red[256];
    const int tid = threadIdx.x;
    float acc = 0.f;
    const float ch = 1.0f / (float)(T_DIM * (H2 - 1) * W2);       // 1/101120
    const float cw = 1.0f / (float)(T_DIM * H2 * (W2 - 1));       // 1/101120
    const float ct = 0.3f / (float)((T_DIM - 1) * H2 * W2);       // 0.3/96000
    for (int b = tid; b < B; b += 256) {
        float p[7] = {0.f, 0.f, 0.f, 0.f, 0.f, 0.f, 0.f};
        for (int band = 0; band < BANDS; ++band) {
            const float* w = ws + (size_t)(b * BANDS + band) * 8;
#pragma unroll
            for (int i = 0; i < 7; ++i) p[i] += w[i];
        }
        const float S0 = p[0], Sx = p[1], Sy = p[2], Sq = p[3];
        const float Th = p[4], Tw = p[5], Tt = p[6];
        const float tot = fmaxf(S0, 1e-6f);
        const float inv = 1.0f / tot;
        const float mux = Sx * inv, muy = Sy * inv;
        const float m2 = mux * mux + muy * muy;
        const float compact = Sq * inv - 2.0f * m2 + m2 * (S0 * inv);
        const float tv = Th * ch + Tw * cw + Tt * ct;
        acc += compact + tv;
    }
    red[tid] = acc;
    __syncthreads();
    for (int s = 128; s > 0; s >>= 1) {
        if (tid < s) red[tid] += red[tid + s];
        __syncthreads();
    }
    if (tid == 0) out[0] = red[0] / (float)B;
}

extern "C" void kernel_launch(void* const* d_in, const int* in_sizes, int n_in,
                              void* d_out, int out_size, void* d_ws, size_t ws_size,
                              hipStream_t stream) {
    const float* scores = (const float*)d_in[0];
    const int B = in_sizes[0] / SAMPLE;  // 256
    float* ws = (float*)d_ws;

    tsr_phase1<<<B * BANDS, BLOCK, 0, stream>>>(scores, ws);
    tsr_finalize<<<1, 256, 0, stream>>>(ws, (float*)d_out, B);
}

// Round 3
// 159.157 us; speedup vs baseline: 1.0158x; 1.0052x over previous
//
#include <hip/hip_runtime.h>

// Problem constants (setup_inputs: B=256, T=16, H=W=160, sms=2 -> t=16, h=w=80)
#define T_DIM 16
#define H2 80
#define W2 80
#define SLICE (H2 * W2)          // 6400 floats per t-slice
#define SAMPLE (T_DIM * SLICE)   // 102400 floats per sample
#define BANDS 5                  // row-bands per sample
#define ROWS_PER_BAND (H2 / BANDS)  // 16 rows
#define BLOCK (ROWS_PER_BAND * W2 / 4)  // 320 threads, one float4 each per slice

__device__ __forceinline__ float4 relu4(float4 v) {
    v.x = fmaxf(v.x, 0.f); v.y = fmaxf(v.y, 0.f);
    v.z = fmaxf(v.z, 0.f); v.w = fmaxf(v.w, 0.f);
    return v;
}

// Phase 1: per-sample linear sums (S0, Sx, Sy, Sq) + TV sums (h, w, t).
// BARRIER-FREE t-loop: neighbor values (h-row, w-boundary scalar) come from
// overlapping global loads (L1/L2 hits -- same lines loaded by adjacent
// threads), not LDS. No __syncthreads in the hot loop means no compiler
// vmcnt(0) drain, so loads pipeline freely across iterations.
// Out-of-range neighbors: offset clamped to own data -> diff contributes 0.
__global__ __launch_bounds__(BLOCK) void tsr_phase1(const float* __restrict__ scores,
                                                    float* __restrict__ ws) {
    __shared__ float red[(BLOCK / 64) * 7];

    const int blk  = blockIdx.x;
    const int b    = blk / BANDS;
    const int band = blk % BANDS;
    const int tid  = threadIdx.x;

    const int y0  = band * ROWS_PER_BAND;
    const int r   = tid / (W2 / 4);   // local row 0..15
    const int cx  = tid % (W2 / 4);   // float4 index within row, 0..19
    const int y   = y0 + r;
    const int xb  = cx * 4;

    const float step = 2.0f / (float)(H2 - 1);   // h == w == 80 -> same step
    const float yy  = -1.0f + (float)y * step;
    const float xx0 = -1.0f + (float)(xb + 0) * step;
    const float xx1 = -1.0f + (float)(xb + 1) * step;
    const float xx2 = -1.0f + (float)(xb + 2) * step;
    const float xx3 = -1.0f + (float)(xb + 3) * step;
    const float yy2 = yy * yy;
    const float cq0 = xx0 * xx0 + yy2;
    const float cq1 = xx1 * xx1 + yy2;
    const float cq2 = xx2 * xx2 + yy2;
    const float cq3 = xx3 * xx3 + yy2;

    const float* sampBase = scores + (size_t)b * SAMPLE;
    const int rowOff = y * W2 + xb;                          // own float4 (floats)
    const int hOff = (y + 1 < H2) ? rowOff + W2 : rowOff;    // h-neighbor row (clamped)
    const int wOff = (xb + 4 < W2) ? rowOff + 4 : rowOff + 3;// w-boundary scalar (clamped)

    float s0 = 0.f, sx = 0.f, sy = 0.f, sq = 0.f;
    float tvh = 0.f, tvw = 0.f, tvt = 0.f;
    float4 prev = make_float4(0.f, 0.f, 0.f, 0.f);

#pragma unroll 4
    for (int t = 0; t < T_DIM; ++t) {
        const float* sl = sampBase + (size_t)t * SLICE;
        const float4 v4 = *(const float4*)(sl + rowOff);
        const float4 h4 = *(const float4*)(sl + hOff);
        const float  wn = sl[wOff];

        const float4 v = relu4(v4);
        const float4 hN = relu4(h4);
        const float  wN = fmaxf(wn, 0.f);

        // linear sums
        const float rs = v.x + v.y + v.z + v.w;
        s0 += rs;
        sy = fmaf(yy, rs, sy);
        sx = fmaf(xx0, v.x, sx); sx = fmaf(xx1, v.y, sx);
        sx = fmaf(xx2, v.z, sx); sx = fmaf(xx3, v.w, sx);
        sq = fmaf(cq0, v.x, sq); sq = fmaf(cq1, v.y, sq);
        sq = fmaf(cq2, v.z, sq); sq = fmaf(cq3, v.w, sq);

        // w-diffs: 3 internal + boundary (clamped -> 0 at row end)
        tvw += fabsf(v.y - v.x) + fabsf(v.z - v.y) + fabsf(v.w - v.z)
             + fabsf(wN - v.w);

        // h-diffs vs next row (clamped -> 0 at y==79)
        tvh += fabsf(hN.x - v.x) + fabsf(hN.y - v.y) +
               fabsf(hN.z - v.z) + fabsf(hN.w - v.w);

        // t-diffs: register-resident
        if (t > 0) {
            tvt += fabsf(v.x - prev.x) + fabsf(v.y - prev.y) +
                   fabsf(v.z - prev.z) + fabsf(v.w - prev.w);
        }
        prev = v;
    }

    // block reduction: wave shuffle, then cross-wave via LDS
    float acc[7] = {s0, sx, sy, sq, tvh, tvw, tvt};
#pragma unroll
    for (int off = 32; off > 0; off >>= 1) {
#pragma unroll
        for (int i = 0; i < 7; ++i) acc[i] += __shfl_down(acc[i], off);
    }
    const int wave = tid >> 6;
    const int lane = tid & 63;
    if (lane == 0) {
#pragma unroll
        for (int i = 0; i < 7; ++i) red[wave * 7 + i] = acc[i];
    }
    __syncthreads();
    if (tid < 7) {
        float s = 0.f;
#pragma unroll
        for (int wv = 0; wv < BLOCK / 64; ++wv) s += red[wv * 7 + tid];
        ws[blk * 8 + tid] = s;  // distinct slot per block -> no init, no atomics
    }
}

// Phase 2: sum band partials per sample, nonlinear combine, batch mean -> scalar
__global__ __launch_bounds__(256) void tsr_finalize(const float* __restrict__ ws,
                                                    float* __restrict__ out, int B) {
    __shared__ float red[256];
    const int tid = threadIdx.x;
    float acc = 0.f;
    const float ch = 1.0f / (float)(T_DIM * (H2 - 1) * W2);       // 1/101120
    const float cw = 1.0f / (float)(T_DIM * H2 * (W2 - 1));       // 1/101120
    const float ct = 0.3f / (float)((T_DIM - 1) * H2 * W2);       // 0.3/96000
    for (int b = tid; b < B; b += 256) {
        float p[7] = {0.f, 0.f, 0.f, 0.f, 0.f, 0.f, 0.f};
        for (int band = 0; band < BANDS; ++band) {
            const float* w = ws + (size_t)(b * BANDS + band) * 8;
#pragma unroll
            for (int i = 0; i < 7; ++i) p[i] += w[i];
        }
        const float S0 = p[0], Sx = p[1], Sy = p[2], Sq = p[3];
        const float Th = p[4], Tw = p[5], Tt = p[6];
        const float tot = fmaxf(S0, 1e-6f);
        const float inv = 1.0f / tot;
        const float mux = Sx * inv, muy = Sy * inv;
        const float m2 = mux * mux + muy * muy;
        const float compact = Sq * inv - 2.0f * m2 + m2 * (S0 * inv);
        const float tv = Th * ch + Tw * cw + Tt * ct;
        acc += compact + tv;
    }
    red[tid] = acc;
    __syncthreads();
    for (int s = 128; s > 0; s >>= 1) {
        if (tid < s) red[tid] += red[tid + s];
        __syncthreads();
    }
    if (tid == 0) out[0] = red[0] / (float)B;
}

extern "C" void kernel_launch(void* const* d_in, const int* in_sizes, int n_in,
                              void* d_out, int out_size, void* d_ws, size_t ws_size,
                              hipStream_t stream) {
    const float* scores = (const float*)d_in[0];
    const int B = in_sizes[0] / SAMPLE;  // 256
    float* ws = (float*)d_ws;

    tsr_phase1<<<B * BANDS, BLOCK, 0, stream>>>(scores, ws);
    tsr_finalize<<<1, 256, 0, stream>>>(ws, (float*)d_out, B);
}